// Round 9
// baseline (274.862 us; speedup 1.0000x reference)
//
#include <hip/hip_runtime.h>

// MatrixFactorization: out[i] = dot(user_i, item_table[dest_i])
// user_i = b + sum_k emb_k[idx_k[i]] @ W_k  (W_k = rows [4k,4k+4) of W[24,32])
// Round 9:
//  (a) depth-2 software pipeline: double-buffered item-row registers (A/B) +
//      2-deep index prefetch -> compute on row_t while row_{t+1} (8 loads) and
//      idx_{t+2} (7 loads) are in flight; compiler emits counted vmcnt, the
//      item latency is hidden under a full trip of LDS/FMA work.
//  (b) dow(7) x sex(2) merged into one 14-entry table (bias folded): 6->5
//      lookups/row; 14 rows x 36-word stride collide only mod 8 -> max 2-way
//      LDS aliasing (free), unlike round 7's 168-entry merge.
//  __launch_bounds__(256,5): 102-VGPR cap >= ~92 live set (no spill),
//  5 blocks/CU; grid 1280 = exactly one resident generation.

#define NF 32
#define LDS_STRIDE 36           // floats per padded table row (144 B, 16B-aligned)
#define NV 181                  // 14 + 24 + 100 + 12 + 31 entries
#define T1_OFF 14               // time
#define T2_OFF 38               // age
#define T3_OFF 138              // month
#define T4_OFF 150              // day

__device__ __forceinline__ float4 ldsf4(const float* p) {
    return *reinterpret_cast<const float4*>(p);
}

__device__ __forceinline__ float dot4(float4 u, float4 v, float a) {
    a = fmaf(u.x, v.x, a);
    a = fmaf(u.y, v.y, a);
    a = fmaf(u.z, v.z, a);
    a = fmaf(u.w, v.w, a);
    return a;
}

#define NTL(P) __builtin_nontemporal_load(P)

struct IdxSet { int j0, j1, j2, j3, j4, j5, jd; };
struct RowSet { float4 q0, q1, q2, q3, q4, q5, q6, q7; };

// one item quad (IV, quad index Q) against 5 tables, 3 acc chains
#define QUAD(IV, Q)                                                  \
    acc0 = dot4(ldsf4(&proj[b0 + (Q) * 4]), IV, acc0);               \
    acc1 = dot4(ldsf4(&proj[b1 + (Q) * 4]), IV, acc1);               \
    acc2 = dot4(ldsf4(&proj[b2 + (Q) * 4]), IV, acc2);               \
    acc0 = dot4(ldsf4(&proj[b3 + (Q) * 4]), IV, acc0);               \
    acc1 = dot4(ldsf4(&proj[b4 + (Q) * 4]), IV, acc1);

#define LOAD_IDX(J, I)                                               \
    J.j0 = NTL(&dow[I]); J.j1 = NTL(&tmi[I]); J.j2 = NTL(&sx[I]);    \
    J.j3 = NTL(&ag[I]);  J.j4 = NTL(&mo[I]);  J.j5 = NTL(&dy[I]);    \
    J.jd = NTL(&dst[I]);

#define LOAD_ROW(R, JD)                                              \
    {                                                                \
        const float4* itp = reinterpret_cast<const float4*>(         \
            item_table + (long long)(JD) * NF);                      \
        R.q0 = itp[0]; R.q1 = itp[1]; R.q2 = itp[2]; R.q3 = itp[3];  \
        R.q4 = itp[4]; R.q5 = itp[5]; R.q6 = itp[6]; R.q7 = itp[7];  \
    }

// Process trip ICUR using row RC / indices JC; prefetch row for INXT (via JN)
// and indices for INXT+tstride (into JC, whose values are consumed first).
#define STEP(RC, RN, JC, JN, ICUR, INXT)                                   \
    {                                                                      \
        const int b0 = (JC.j2 * 7 + JC.j0)   * LDS_STRIDE;                 \
        const int b1 = (T1_OFF + JC.j1)      * LDS_STRIDE;                 \
        const int b2 = (T2_OFF + JC.j3)      * LDS_STRIDE;                 \
        const int b3 = (T3_OFF + JC.j4)      * LDS_STRIDE;                 \
        const int b4 = (T4_OFF + JC.j5)      * LDS_STRIDE;                 \
        if ((INXT) < n) {                                                  \
            LOAD_ROW(RN, JN.jd)                                            \
            const int i3 = (INXT) + tstride;                              \
            if (i3 < n) { LOAD_IDX(JC, i3) }                               \
        }                                                                  \
        asm volatile("" ::: "memory");                                     \
        float acc0 = 0.0f, acc1 = 0.0f, acc2 = 0.0f;                       \
        QUAD(RC.q0, 0) QUAD(RC.q1, 1) QUAD(RC.q2, 2) QUAD(RC.q3, 3)        \
        QUAD(RC.q4, 4) QUAD(RC.q5, 5) QUAD(RC.q6, 6) QUAD(RC.q7, 7)        \
        __builtin_nontemporal_store(acc0 + acc1 + acc2, &out[ICUR]);       \
    }

__global__ __launch_bounds__(256, 5)
void mf_kernel(const int* __restrict__ dow, const int* __restrict__ tmi,
               const int* __restrict__ sx,  const int* __restrict__ ag,
               const int* __restrict__ mo,  const int* __restrict__ dy,
               const int* __restrict__ dst,
               const float* __restrict__ e_dow,   const float* __restrict__ e_time,
               const float* __restrict__ e_sex,   const float* __restrict__ e_age,
               const float* __restrict__ e_month, const float* __restrict__ e_day,
               const float* __restrict__ W, const float* __restrict__ bvec,
               const float* __restrict__ item_table,
               float* __restrict__ out, int n)
{
    __shared__ float proj[NV * LDS_STRIDE];   // 26,064 B

    // ---- Stage 1: build projected tables in LDS ----
    // W row blocks: dow 0-3, time 4-7, sex 8-11, age 12-15, month 16-19, day 20-23
    const int tid = threadIdx.x;
    for (int t = tid; t < NV * NF; t += blockDim.x) {
        const int entry = t >> 5;
        const int f     = t & 31;
        float acc;
        if (entry < T1_OFF) {                       // dow x sex (+bias)
            const int s  = entry / 7;
            const int d0 = entry - s * 7;
            acc = bvec[f];
            #pragma unroll
            for (int d = 0; d < 4; ++d) {
                acc = fmaf(e_dow[d0 * 4 + d], W[(0 + d) * NF + f], acc);
                acc = fmaf(e_sex[s * 4 + d],  W[(8 + d) * NF + f], acc);
            }
        } else if (entry < T2_OFF) {                // time
            const int v = entry - T1_OFF;
            acc = 0.0f;
            #pragma unroll
            for (int d = 0; d < 4; ++d)
                acc = fmaf(e_time[v * 4 + d], W[(4 + d) * NF + f], acc);
        } else if (entry < T3_OFF) {                // age
            const int v = entry - T2_OFF;
            acc = 0.0f;
            #pragma unroll
            for (int d = 0; d < 4; ++d)
                acc = fmaf(e_age[v * 4 + d], W[(12 + d) * NF + f], acc);
        } else if (entry < T4_OFF) {                // month
            const int v = entry - T3_OFF;
            acc = 0.0f;
            #pragma unroll
            for (int d = 0; d < 4; ++d)
                acc = fmaf(e_month[v * 4 + d], W[(16 + d) * NF + f], acc);
        } else {                                    // day
            const int v = entry - T4_OFF;
            acc = 0.0f;
            #pragma unroll
            for (int d = 0; d < 4; ++d)
                acc = fmaf(e_day[v * 4 + d], W[(20 + d) * NF + f], acc);
        }
        proj[entry * LDS_STRIDE + f] = acc;
    }
    __syncthreads();

    // ---- Stage 2: depth-2 pipelined grid-stride loop ----
    const int tstride = gridDim.x * blockDim.x;
    int i = blockIdx.x * blockDim.x + tid;
    if (i >= n) return;

    IdxSet P, Q;
    RowSet A, B;

    // prologue: idx(t0) -> row(t0); idx(t1)
    LOAD_IDX(P, i)
    LOAD_ROW(A, P.jd)          // waits for P, issues A-row
    int i2 = i + tstride;
    if (i2 < n) { LOAD_IDX(Q, i2) }

    for (;;) {
        STEP(A, B, P, Q, i, i2)
        if (i2 >= n) break;
        i = i2; i2 += tstride;
        STEP(B, A, Q, P, i, i2)
        if (i2 >= n) break;
        i = i2; i2 += tstride;
    }
}

extern "C" void kernel_launch(void* const* d_in, const int* in_sizes, int n_in,
                              void* d_out, int out_size, void* d_ws, size_t ws_size,
                              hipStream_t stream) {
    const int* dow = (const int*)d_in[0];
    const int* tmi = (const int*)d_in[1];
    const int* sx  = (const int*)d_in[2];
    const int* ag  = (const int*)d_in[3];
    const int* mo  = (const int*)d_in[4];
    const int* dy  = (const int*)d_in[5];
    const int* dst = (const int*)d_in[6];
    const float* e_dow   = (const float*)d_in[7];
    const float* e_time  = (const float*)d_in[8];
    const float* e_sex   = (const float*)d_in[9];
    const float* e_age   = (const float*)d_in[10];
    const float* e_month = (const float*)d_in[11];
    const float* e_day   = (const float*)d_in[12];
    const float* W       = (const float*)d_in[13];
    const float* bvec    = (const float*)d_in[14];
    const float* item    = (const float*)d_in[15];
    float* out = (float*)d_out;
    const int n = in_sizes[0];

    // 1280 blocks = 5 blocks/CU resident (VGPR-capped at 5 waves/SIMD),
    // single generation; ~6.4 grid-stride trips/thread at N=2M.
    dim3 grid(1280), block(256);
    mf_kernel<<<grid, block, 0, stream>>>(dow, tmi, sx, ag, mo, dy, dst,
                                          e_dow, e_time, e_sex, e_age, e_month, e_day,
                                          W, bvec, item, out, n);
}

// Round 14
// 167.534 us; speedup vs baseline: 1.6406x; 1.6406x over previous
//
#include <hip/hip_runtime.h>

// MatrixFactorization: out[i] = dot(user_i, item_table[dest_i])
// user_i = b + sum_k emb_k[idx_k[i]] @ W_k  (W_k = rows [4k,4k+4) of W[24,32])
// Round 10 = round 8 skeleton (no cross-iteration register buffers — round 9
// proved those spill to scratch on this allocator) + two spill-free levers:
//  (a) dow(7) x sex(2) merged -> 14-entry table (bias folded): 6->5 lookups,
//      48->40 ds_read_b128 per row. 14 rows @ stride 36 (9 coprime 8) keep
//      the bank-rotation property -> conflict-neutral, unlike r7's 168-entry.
//  (b) 512-thread blocks, __launch_bounds__(512,8), grid 1024 = 4 blocks/CU
//      x 8 waves = 32 waves/CU requested; LDS 4 x 26 KB fits; VGPR cap 64 >=
//      the ~40 the allocator picks.

#define NF 32
#define LDS_STRIDE 36           // floats per padded table row (144 B, 16B-aligned)
#define NV 181                  // 14 + 24 + 100 + 12 + 31 entries
#define T1_OFF 14               // time
#define T2_OFF 38               // age
#define T3_OFF 138              // month
#define T4_OFF 150              // day

__device__ __forceinline__ float4 ldsf4(const float* p) {
    return *reinterpret_cast<const float4*>(p);
}

__device__ __forceinline__ float dot4(float4 u, float4 v, float a) {
    a = fmaf(u.x, v.x, a);
    a = fmaf(u.y, v.y, a);
    a = fmaf(u.z, v.z, a);
    a = fmaf(u.w, v.w, a);
    return a;
}

// one item quad (IV, quad index Q) against 5 tables, 3 acc chains
#define QUAD(IV, Q)                                                  \
    acc0 = dot4(ldsf4(&proj[b0 + (Q) * 4]), IV, acc0);               \
    acc1 = dot4(ldsf4(&proj[b1 + (Q) * 4]), IV, acc1);               \
    acc2 = dot4(ldsf4(&proj[b2 + (Q) * 4]), IV, acc2);               \
    acc0 = dot4(ldsf4(&proj[b3 + (Q) * 4]), IV, acc0);               \
    acc1 = dot4(ldsf4(&proj[b4 + (Q) * 4]), IV, acc1);

#define NTL(P) __builtin_nontemporal_load(P)

__global__ __launch_bounds__(512, 8)
void mf_kernel(const int* __restrict__ dow, const int* __restrict__ tmi,
               const int* __restrict__ sx,  const int* __restrict__ ag,
               const int* __restrict__ mo,  const int* __restrict__ dy,
               const int* __restrict__ dst,
               const float* __restrict__ e_dow,   const float* __restrict__ e_time,
               const float* __restrict__ e_sex,   const float* __restrict__ e_age,
               const float* __restrict__ e_month, const float* __restrict__ e_day,
               const float* __restrict__ W, const float* __restrict__ bvec,
               const float* __restrict__ item_table,
               float* __restrict__ out, int n)
{
    __shared__ float proj[NV * LDS_STRIDE];   // 26,064 B

    // ---- Stage 1: build projected tables in LDS ----
    // W row blocks: dow 0-3, time 4-7, sex 8-11, age 12-15, month 16-19, day 20-23
    const int tid = threadIdx.x;
    for (int t = tid; t < NV * NF; t += blockDim.x) {
        const int entry = t >> 5;
        const int f     = t & 31;
        float acc;
        if (entry < T1_OFF) {                       // dow x sex (+bias)
            const int s  = entry / 7;
            const int d0 = entry - s * 7;
            acc = bvec[f];
            #pragma unroll
            for (int d = 0; d < 4; ++d) {
                acc = fmaf(e_dow[d0 * 4 + d], W[(0 + d) * NF + f], acc);
                acc = fmaf(e_sex[s * 4 + d],  W[(8 + d) * NF + f], acc);
            }
        } else if (entry < T2_OFF) {                // time
            const int v = entry - T1_OFF;
            acc = 0.0f;
            #pragma unroll
            for (int d = 0; d < 4; ++d)
                acc = fmaf(e_time[v * 4 + d], W[(4 + d) * NF + f], acc);
        } else if (entry < T3_OFF) {                // age
            const int v = entry - T2_OFF;
            acc = 0.0f;
            #pragma unroll
            for (int d = 0; d < 4; ++d)
                acc = fmaf(e_age[v * 4 + d], W[(12 + d) * NF + f], acc);
        } else if (entry < T4_OFF) {                // month
            const int v = entry - T3_OFF;
            acc = 0.0f;
            #pragma unroll
            for (int d = 0; d < 4; ++d)
                acc = fmaf(e_month[v * 4 + d], W[(16 + d) * NF + f], acc);
        } else {                                    // day
            const int v = entry - T4_OFF;
            acc = 0.0f;
            #pragma unroll
            for (int d = 0; d < 4; ++d)
                acc = fmaf(e_day[v * 4 + d], W[(20 + d) * NF + f], acc);
        }
        proj[entry * LDS_STRIDE + f] = acc;
    }
    __syncthreads();

    // ---- Stage 2: 1 row/thread, grid-stride, 2-deep index pipeline ----
    const int tstride = gridDim.x * blockDim.x;
    int i = blockIdx.x * blockDim.x + tid;
    if (i >= n) return;

    // prologue: indices for first trip
    int j0 = NTL(&dow[i]), j1 = NTL(&tmi[i]), j2 = NTL(&sx[i]),
        j3 = NTL(&ag[i]),  j4 = NTL(&mo[i]),  j5 = NTL(&dy[i]),
        jd = NTL(&dst[i]);

    for (;;) {
        const int b0 = (j2 * 7 + j0)      * LDS_STRIDE;   // dow x sex
        const int b1 = (T1_OFF + j1)      * LDS_STRIDE;   // time
        const int b2 = (T2_OFF + j3)      * LDS_STRIDE;   // age
        const int b3 = (T3_OFF + j4)      * LDS_STRIDE;   // month
        const int b4 = (T4_OFF + j5)      * LDS_STRIDE;   // day
        const float4* it = reinterpret_cast<const float4*>(item_table + (long long)jd * NF);

        // whole 128 B item row (one L2 line) in one burst
        float4 iv0 = it[0];
        float4 iv1 = it[1];
        float4 iv2 = it[2];
        float4 iv3 = it[3];
        float4 iv4 = it[4];
        float4 iv5 = it[5];
        float4 iv6 = it[6];
        float4 iv7 = it[7];

        // prefetch next trip's indices while the item row is in flight
        const int ni = i + tstride;
        const bool more = ni < n;          // wave-uniform (n, stride multiples of 64)
        if (more) {
            j0 = NTL(&dow[ni]); j1 = NTL(&tmi[ni]); j2 = NTL(&sx[ni]);
            j3 = NTL(&ag[ni]);  j4 = NTL(&mo[ni]);  j5 = NTL(&dy[ni]);
            jd = NTL(&dst[ni]);
        }

        // fence: no load may be sunk below this point -> one batched vmcnt wait
        asm volatile("" ::: "memory");

        float acc0 = 0.0f, acc1 = 0.0f, acc2 = 0.0f;
        QUAD(iv0, 0)
        QUAD(iv1, 1)
        QUAD(iv2, 2)
        QUAD(iv3, 3)
        QUAD(iv4, 4)
        QUAD(iv5, 5)
        QUAD(iv6, 6)
        QUAD(iv7, 7)
        __builtin_nontemporal_store(acc0 + acc1 + acc2, &out[i]);

        if (!more) break;
        i = ni;
    }
}

extern "C" void kernel_launch(void* const* d_in, const int* in_sizes, int n_in,
                              void* d_out, int out_size, void* d_ws, size_t ws_size,
                              hipStream_t stream) {
    const int* dow = (const int*)d_in[0];
    const int* tmi = (const int*)d_in[1];
    const int* sx  = (const int*)d_in[2];
    const int* ag  = (const int*)d_in[3];
    const int* mo  = (const int*)d_in[4];
    const int* dy  = (const int*)d_in[5];
    const int* dst = (const int*)d_in[6];
    const float* e_dow   = (const float*)d_in[7];
    const float* e_time  = (const float*)d_in[8];
    const float* e_sex   = (const float*)d_in[9];
    const float* e_age   = (const float*)d_in[10];
    const float* e_month = (const float*)d_in[11];
    const float* e_day   = (const float*)d_in[12];
    const float* W       = (const float*)d_in[13];
    const float* bvec    = (const float*)d_in[14];
    const float* item    = (const float*)d_in[15];
    float* out = (float*)d_out;
    const int n = in_sizes[0];

    // 1024 blocks x 512 threads = 4 blocks/CU x 8 waves = 32 waves/CU;
    // 524,288 threads -> exactly 4 grid-stride trips at N=2M.
    dim3 grid(1024), block(512);
    mf_kernel<<<grid, block, 0, stream>>>(dow, tmi, sx, ag, mo, dy, dst,
                                          e_dow, e_time, e_sex, e_age, e_month, e_day,
                                          W, bvec, item, out, n);
}